// Round 1
// baseline (249.115 us; speedup 1.0000x reference)
//
#include <hip/hip_runtime.h>
#include <math.h>

// img (16,8,512,512) fp32, params (16,3) fp32, out (16,8,512,512) fp32.
// Restructure vs previous version: ONE (batch, channel, tile) per block —
// no 8-phase channel loop, no double buffer, one barrier per block.
// 32768 independent blocks give 8 blocks/CU (32 waves, 100% occupancy cap)
// so DMA latency hides via TLP instead of a 2-deep vmcnt pipeline.
// All per-pixel fp math is bit-identical to the previous (verified) kernel.
constexpr int B = 16, C = 8, H = 512, W = 512;
constexpr int HW = H * W;
constexpr int TILE = 32;           // 32x32 output tile per block
constexpr int ROWS = 48;           // staged source rows (bbox span <= 46)
constexpr int LSTR = 79;           // LDS row stride (floats): bank=(15y+x)&31
constexpr int BUFSZ = ROWS * LSTR; // 3792 floats = 14.8 KiB, single buffer

// Async global->LDS: per-lane global address, LDS dst = uniform base + lane*4.
__device__ __forceinline__ void dma4(const float* g, float* l) {
    __builtin_amdgcn_global_load_lds(
        (const __attribute__((address_space(1))) unsigned int*)g,
        (__attribute__((address_space(3))) unsigned int*)l,
        4, 0, 0);
}

__global__ __launch_bounds__(256, 8) void grid_sampler_kernel(
    const float* __restrict__ img,
    const float* __restrict__ params,
    float* __restrict__ out) {
    __shared__ float lds[BUFSZ];
    const int tid = threadIdx.x;

    // Bijective XCD swizzle: 32768 blocks = 8 XCDs x 4096. Consecutive
    // logical ids = same channel, x-adjacent tiles (shared staging margins)
    // -> same XCD L2. Each XCD chunk of 4096 = two full (b,ch) planes.
    const int blk = (int)blockIdx.x;
    const int l   = (blk & 7) * 4096 + (blk >> 3);
    const int b   = l >> 11;             // (b, ch, ty, tx) ordering
    const int ch  = (l >> 8) & 7;
    const int tt  = l & 255;
    const int ty0 = (tt >> 4) * TILE;
    const int tx0 = (tt & 15) * TILE;

    // Zero col 64 of every row: the only un-staged LDS cell a (zero-weight)
    // tap can reach via the xi<=63 clamp; must be finite.
    if (tid < ROWS) lds[tid * LSTR + 64] = 0.0f;

    // Wave-uniform per-batch params.
    const float tpx = params[b * 3 + 0] * (1.0f / W);
    const float tpy = params[b * 3 + 1] * (1.0f / H);
    const float th  = params[b * 3 + 2];
    const float c = cosf(th), s = sinf(th);

    // Identical fp expression for bbox corners and per-pixel sampling; gx/gy
    // monotone in x,y (per fixed other coord) so corner min bounds every pixel.
    auto srcxy = [&](float x, float y, float& ix, float& iy) {
        float xs = (2.0f * x + 1.0f) * (1.0f / W) - 1.0f;
        float ys = (2.0f * y + 1.0f) * (1.0f / H) - 1.0f;
        float gx = c * xs - s * ys + tpx;
        float gy = s * xs + c * ys + tpy;
        ix = ((gx + 1.0f) * (float)W - 1.0f) * 0.5f;
        iy = ((gy + 1.0f) * (float)H - 1.0f) * 0.5f;
    };

    float ixa, iya, ixb, iyb, ixc, iyc, ixd, iyd;
    srcxy((float)tx0,             (float)ty0,             ixa, iya);
    srcxy((float)(tx0 + TILE-1),  (float)ty0,             ixb, iyb);
    srcxy((float)tx0,             (float)(ty0 + TILE-1),  ixc, iyc);
    srcxy((float)(tx0 + TILE-1),  (float)(ty0 + TILE-1),  ixd, iyd);
    const float ixmin = fminf(fminf(ixa, ixb), fminf(ixc, ixd));
    const float iymin = fminf(fminf(iya, iyb), fminf(iyc, iyd));
    const int xlo = min(max((int)floorf(ixmin), 0), W - 1);
    const int ylo = min(max((int)floorf(iymin), 0), H - 1);
    // 1-texel left margin: LDS col ln holds image col clamp(xls+ln, 0, W-1);
    // duplication only ever feeds 0-weight taps.
    const int xls = xlo - 1;             // may be -1
    const int yls = min(ylo, H - ROWS);  // rows always in-image

    // Stage this block's single channel: wave wv stages rows [12wv, 12wv+12).
    const size_t plane = (size_t)(b * C + ch) * HW;
    const int wv = tid >> 6, ln = tid & 63;
    const int scol = min(max(xls + ln, 0), W - 1);
    const float* sbase = img + plane + (size_t)yls * W + scol;
#pragma unroll
    for (int j2 = 0; j2 < 12; ++j2) {
        const int r = 12 * wv + j2;
        dma4(sbase + (size_t)r * W, &lds[r * LSTR]);
    }

    // Thread -> one output row, 4 consecutive cols (float4 store).
    const int oy  = ty0 + (tid >> 3);
    const int oxb = tx0 + (tid & 7) * 4;

    asm volatile("s_waitcnt vmcnt(0) lgkmcnt(0)\n\ts_barrier" ::: "memory");

    float4 v;
#pragma unroll
    for (int j = 0; j < 4; ++j) {
        float ix, iy;
        srcxy((float)(oxb + j), (float)oy, ix, iy);
        const float x0f = floorf(ix), y0f = floorf(iy);
        const int x0 = (int)x0f, y0 = (int)y0f;
        const int x1 = x0 + 1,  y1 = y0 + 1;
        const float wx1 = ix - x0f, wx0 = 1.0f - wx1;
        const float wy1 = iy - y0f, wy0 = 1.0f - wy1;
        const float vx0 = (x0 >= 0 && x0 < W) ? 1.0f : 0.0f;
        const float vx1 = (x1 >= 0 && x1 < W) ? 1.0f : 0.0f;
        const float vy0 = (y0 >= 0 && y0 < H) ? 1.0f : 0.0f;
        const float vy1 = (y1 >= 0 && y1 < H) ? 1.0f : 0.0f;
        const float w00 = wy0 * wx0 * vy0 * vx0;
        const float w01 = wy0 * wx1 * vy0 * vx1;
        const float w10 = wy1 * wx0 * vy1 * vx0;
        const float w11 = wy1 * wx1 * vy1 * vx1;
        // Valid x0 >= xlo -> xi = x0-xls in [1,48]; x0=-1 (0-wt) -> xi=0 and
        // the x1 tap reads LDS col 1 = image col 0 (correct). Far-OOB clamps
        // hit staged/zeroed finite cells with 0 weight.
        const int xi  = min(max(x0 - xls, 0), 63);
        const int yi0 = min(max(y0 - yls, 0), ROWS - 1);
        const int yi1 = min(max(y1 - yls, 0), ROWS - 1);
        const int a0 = yi0 * LSTR + xi;
        const int a1 = yi1 * LSTR + xi;
        const float t00 = lds[a0], t01 = lds[a0 + 1];
        const float t10 = lds[a1], t11 = lds[a1 + 1];
        ((float*)&v)[j] = t00 * w00 + t01 * w01 + t10 * w10 + t11 * w11;
    }
    *(float4*)(out + plane + oy * W + oxb) = v;
}

extern "C" void kernel_launch(void* const* d_in, const int* in_sizes, int n_in,
                              void* d_out, int out_size, void* d_ws, size_t ws_size,
                              hipStream_t stream) {
    const float* img    = (const float*)d_in[0];
    const float* params = (const float*)d_in[1];
    float*       out    = (float*)d_out;

    constexpr int grid = B * C * (H / TILE) * (W / TILE);   // 32768 blocks
    grid_sampler_kernel<<<grid, 256, 0, stream>>>(img, params, out);
}

// Round 2
// 242.857 us; speedup vs baseline: 1.0258x; 1.0258x over previous
//
#include <hip/hip_runtime.h>
#include <math.h>

// img (16,8,512,512) fp32, params (16,3) fp32, out (16,8,512,512) fp32.
// Round 2: one (batch, channel-PAIR, tile) per block. The per-pixel weight /
// address setup (the VALU hot spot exposed in round 1: VALUBusy 90%) is
// computed once and reused for both channels; both channel tiles are staged
// up-front (24 DMAs/wave) so there is no multi-phase vmcnt convoy — one
// vmcnt(12) for ch A (ch B still in flight), one vmcnt(1) for ch B.
// launch_bounds(256,5) matches the LDS cap (5 blocks/CU) and lifts the
// 64-VGPR straitjacket that caused 16-VGPR remat thrash in round 1.
// All per-pixel fp math is bit-identical to the verified round-0/1 kernels.
constexpr int B = 16, C = 8, H = 512, W = 512;
constexpr int HW = H * W;
constexpr int TILE = 32;           // 32x32 output tile per block
constexpr int ROWS = 48;           // staged source rows (bbox span <= 46)
constexpr int LSTR = 79;           // LDS row stride (floats): bank=(15y+x)&31
constexpr int BUFSZ = ROWS * LSTR; // 3792 floats = 14.8 KiB per channel

// Async global->LDS: per-lane global address, LDS dst = uniform base + lane*4.
__device__ __forceinline__ void dma4(const float* g, float* l) {
    __builtin_amdgcn_global_load_lds(
        (const __attribute__((address_space(1))) unsigned int*)g,
        (__attribute__((address_space(3))) unsigned int*)l,
        4, 0, 0);
}

__global__ __launch_bounds__(256, 5) void grid_sampler_kernel(
    const float* __restrict__ img,
    const float* __restrict__ params,
    float* __restrict__ out) {
    __shared__ float lds[2][BUFSZ];
    const int tid = threadIdx.x;

    // Bijective XCD swizzle: 16384 blocks = 8 XCDs x 2048. Consecutive
    // logical ids = same channel pair, x-adjacent tiles (overlapping staging
    // margins) -> same XCD L2.
    const int blk = (int)blockIdx.x;
    const int l   = (blk & 7) * 2048 + (blk >> 3);
    const int b   = l >> 10;             // (b, ch-pair, ty, tx) ordering
    const int ch2 = (l >> 8) & 3;
    const int tt  = l & 255;
    const int ty0 = (tt >> 4) * TILE;
    const int tx0 = (tt & 15) * TILE;

    // Zero col 64 of every row in both buffers: the only un-staged LDS cell a
    // (zero-weight) tap can reach via the xi<=63 clamp; must be finite.
    if (tid < 96) {
        const int bb = tid / ROWS, r = tid % ROWS;
        lds[bb][r * LSTR + 64] = 0.0f;
    }

    // Wave-uniform per-batch params.
    const float tpx = params[b * 3 + 0] * (1.0f / W);
    const float tpy = params[b * 3 + 1] * (1.0f / H);
    const float th  = params[b * 3 + 2];
    const float c = cosf(th), s = sinf(th);

    // Identical fp expression for bbox corners and per-pixel sampling; gx/gy
    // monotone in x,y (per fixed other coord) so corner min bounds every pixel.
    auto srcxy = [&](float x, float y, float& ix, float& iy) {
        float xs = (2.0f * x + 1.0f) * (1.0f / W) - 1.0f;
        float ys = (2.0f * y + 1.0f) * (1.0f / H) - 1.0f;
        float gx = c * xs - s * ys + tpx;
        float gy = s * xs + c * ys + tpy;
        ix = ((gx + 1.0f) * (float)W - 1.0f) * 0.5f;
        iy = ((gy + 1.0f) * (float)H - 1.0f) * 0.5f;
    };

    float ixa, iya, ixb, iyb, ixc, iyc, ixd, iyd;
    srcxy((float)tx0,             (float)ty0,             ixa, iya);
    srcxy((float)(tx0 + TILE-1),  (float)ty0,             ixb, iyb);
    srcxy((float)tx0,             (float)(ty0 + TILE-1),  ixc, iyc);
    srcxy((float)(tx0 + TILE-1),  (float)(ty0 + TILE-1),  ixd, iyd);
    const float ixmin = fminf(fminf(ixa, ixb), fminf(ixc, ixd));
    const float iymin = fminf(fminf(iya, iyb), fminf(iyc, iyd));
    const int xlo = min(max((int)floorf(ixmin), 0), W - 1);
    const int ylo = min(max((int)floorf(iymin), 0), H - 1);
    // 1-texel left margin: LDS col ln holds image col clamp(xls+ln, 0, W-1);
    // duplication only ever feeds 0-weight taps.
    const int xls = xlo - 1;             // may be -1
    const int yls = min(ylo, H - ROWS);  // rows always in-image

    // Stage BOTH channels of the pair: wave wv stages rows [12wv, 12wv+12).
    const size_t plane = (size_t)(b * C + 2 * ch2) * HW;  // channel A plane
    const int wv = tid >> 6, ln = tid & 63;
    const int scol = min(max(xls + ln, 0), W - 1);
    const float* sbase = img + plane + (size_t)yls * W + scol;
#pragma unroll
    for (int j2 = 0; j2 < 12; ++j2) {
        const int r = 12 * wv + j2;
        dma4(sbase + (size_t)r * W, &lds[0][r * LSTR]);
    }
#pragma unroll
    for (int j2 = 0; j2 < 12; ++j2) {
        const int r = 12 * wv + j2;
        dma4(sbase + (size_t)HW + (size_t)r * W, &lds[1][r * LSTR]);
    }

    // Per-pixel setup ONCE (overlaps the DMA flight), reused by both channels.
    const int oy  = ty0 + (tid >> 3);
    const int oxb = tx0 + (tid & 7) * 4;
    int   a0[4], a1[4];
    float w00[4], w01[4], w10[4], w11[4];
#pragma unroll
    for (int j = 0; j < 4; ++j) {
        float ix, iy;
        srcxy((float)(oxb + j), (float)oy, ix, iy);
        const float x0f = floorf(ix), y0f = floorf(iy);
        const int x0 = (int)x0f, y0 = (int)y0f;
        const int x1 = x0 + 1,  y1 = y0 + 1;
        const float wx1 = ix - x0f, wx0 = 1.0f - wx1;
        const float wy1 = iy - y0f, wy0 = 1.0f - wy1;
        const float vx0 = (x0 >= 0 && x0 < W) ? 1.0f : 0.0f;
        const float vx1 = (x1 >= 0 && x1 < W) ? 1.0f : 0.0f;
        const float vy0 = (y0 >= 0 && y0 < H) ? 1.0f : 0.0f;
        const float vy1 = (y1 >= 0 && y1 < H) ? 1.0f : 0.0f;
        w00[j] = wy0 * wx0 * vy0 * vx0;
        w01[j] = wy0 * wx1 * vy0 * vx1;
        w10[j] = wy1 * wx0 * vy1 * vx0;
        w11[j] = wy1 * wx1 * vy1 * vx1;
        // Valid x0 >= xlo -> xi = x0-xls in [1,48]; x0=-1 (0-wt) -> xi=0 and
        // the x1 tap reads LDS col 1 = image col 0 (correct). Far-OOB clamps
        // hit staged/zeroed finite cells with 0 weight.
        const int xi  = min(max(x0 - xls, 0), 63);
        const int yi0 = min(max(y0 - yls, 0), ROWS - 1);
        const int yi1 = min(max(y1 - yls, 0), ROWS - 1);
        a0[j] = yi0 * LSTR + xi;
        a1[j] = yi1 * LSTR + xi;
    }
    const int ooff = oy * W + oxb;

    // Channel A: its 12 DMAs are the 12 OLDEST; ch B's 12 stay in flight.
    asm volatile("s_waitcnt vmcnt(12) lgkmcnt(0)\n\ts_barrier" ::: "memory");
    {
        const float* bp = &lds[0][0];
        float4 v;
#pragma unroll
        for (int j = 0; j < 4; ++j) {
            const float t00 = bp[a0[j]], t01 = bp[a0[j] + 1];
            const float t10 = bp[a1[j]], t11 = bp[a1[j] + 1];
            ((float*)&v)[j] = t00 * w00[j] + t01 * w01[j]
                            + t10 * w10[j] + t11 * w11[j];
        }
        *(float4*)(out + plane + ooff) = v;
    }
    // Channel B: allow the newest VMEM op (our ch-A store) to stay in flight;
    // vmcnt is issue-ordered, so vmcnt(1) completes all 12 ch-B DMAs.
    asm volatile("s_waitcnt vmcnt(1) lgkmcnt(0)\n\ts_barrier" ::: "memory");
    {
        const float* bp = &lds[1][0];
        float4 v;
#pragma unroll
        for (int j = 0; j < 4; ++j) {
            const float t00 = bp[a0[j]], t01 = bp[a0[j] + 1];
            const float t10 = bp[a1[j]], t11 = bp[a1[j] + 1];
            ((float*)&v)[j] = t00 * w00[j] + t01 * w01[j]
                            + t10 * w10[j] + t11 * w11[j];
        }
        *(float4*)(out + plane + HW + ooff) = v;
    }
}

extern "C" void kernel_launch(void* const* d_in, const int* in_sizes, int n_in,
                              void* d_out, int out_size, void* d_ws, size_t ws_size,
                              hipStream_t stream) {
    const float* img    = (const float*)d_in[0];
    const float* params = (const float*)d_in[1];
    float*       out    = (float*)d_out;

    constexpr int grid = B * (C / 2) * (H / TILE) * (W / TILE);  // 16384 blocks
    grid_sampler_kernel<<<grid, 256, 0, stream>>>(img, params, out);
}